// Round 13
// baseline (297.397 us; speedup 1.0000x reference)
//
#include <hip/hip_runtime.h>

// Problem constants: nframes=8, nloc=8192, nnei=128, nall=16384, ntypes=4,
// nspline=2000. rmin=0, hh=f32(0.005), rcut=6.0.
constexpr int NFRAMES = 8;
constexpr int NLOC    = 8192;
constexpr int NNEI    = 128;
constexpr int NALL    = 16384;
constexpr int NTYPES  = 4;
constexpr int NSPLINE = 2000;
constexpr int KLIVE   = 1200;   // rr<6 => uu=rr*200<1200 => live bins [0,1200)
constexpr int KBLK    = 16;     // chunks (blocks) per (frame,type) bucket

// Opaque dataflow barrier: keeps the verified f32 rounding chain intact.
#define FP_BAR(x) asm volatile("" : "+v"(x))

__global__ __launch_bounds__(256) void pack_kernel(
    const float* __restrict__ coord, const int* __restrict__ atype,
    float4* __restrict__ pack)
{
    int t = blockIdx.x * 256 + threadIdx.x;   // grid sized exactly
    float4 v;
    v.x = coord[3 * (size_t)t + 0];
    v.y = coord[3 * (size_t)t + 1];
    v.z = coord[3 * (size_t)t + 2];
    v.w = __int_as_float(atype[t]);
    pack[t] = v;
}

__global__ void zero_counts_kernel(int* __restrict__ cnts)
{
    if (threadIdx.x < NFRAMES * NTYPES) cnts[threadIdx.x] = 0;
}

// Group locs by (frame, i-type) so whole blocks share one 76.8KB tab slice.
__global__ __launch_bounds__(256) void bucket_kernel(
    const int* __restrict__ atype, int* __restrict__ perm,
    int* __restrict__ cnts)
{
    int t = blockIdx.x * 256 + threadIdx.x;   // 0..65535
    int f = t >> 13;
    int i = t & (NLOC - 1);
    int ty = atype[(size_t)f * NALL + i];
    int b  = f * NTYPES + ty;
    int pos = atomicAdd(&cnts[b], 1);
    perm[(size_t)b * NLOC + pos] = i;         // capacity 8192/bucket is safe
}

// VERIFIED ref chain (r11, absmax 3.8e-6 — DO NOT TOUCH):
//   ss = fma(dz,dz, fma(dx,dx, dy*dy)); rr = CR sqrtf; uu = rr * f32(1/hh);
//   idx = trunc(uu); poly/sum in f64 (post-bin). Energy zero iff
//   !valid | rr>=6 (idx>NSPLINE is subsumed: idx>2000 => rr>=10>6).
//   Live lanes have idx in [0,1199] so coef comes from the LDS slice.
__device__ __forceinline__ double nb_energy_lds(
    float4 c, bool valid, float xl, float yl, float zl,
    float rmin, float recip, const float4* __restrict__ ltab)
{
    float dx = c.x - xl;  FP_BAR(dx);
    float dy = c.y - yl;  FP_BAR(dy);
    float dz = c.z - zl;  FP_BAR(dz);
    float my = dy * dy;                    FP_BAR(my);
    float t1 = __builtin_fmaf(dx, dx, my); FP_BAR(t1);   // canonical inner
    float ss = __builtin_fmaf(dz, dz, t1); FP_BAR(ss);
    float rr = sqrtf(ss);                  FP_BAR(rr);   // CR
    float num = rr - rmin;               FP_BAR(num);    // rmin=0: num==rr
    float uu  = num * recip;             FP_BAR(uu);     // recip-mul form
    double e = 0.0;
    if (valid && rr < 6.0f) {
        int    idx = (int)uu;                // in [0,1199] here
        double t   = (double)uu - (double)idx;           // exact (Sterbenz)
        int    tj  = __float_as_int(c.w);
        float4 cf  = ltab[tj * KLIVE + idx];             // ds_read_b128
        e = (((double)cf.x * t + (double)cf.y) * t + (double)cf.z) * t
            + (double)cf.w;
    }
    return e;
}

// r13: coef gathers served from LDS. One block per (frame,itype,chunk);
// 1024 threads = 16 waves; each wave covers 2 locs (halves of the wave).
// LDS 76.8KB -> 2 blocks/CU, 32 waves/CU. Scattered L2 requests drop from
// ~15M (pack+coef) to ~8.4M (pack) + 0.6M staging.
__global__ __launch_bounds__(1024) void pairtab_lds_kernel(
    const float4* __restrict__ pack,
    const float*  __restrict__ tab,       // [NTYPES][NTYPES][NSPLINE][4]
    const float*  __restrict__ tab_info,  // [rmin, hh, nspline, ntypes]
    const int*    __restrict__ nlist,     // [NFRAMES][NLOC][NNEI] int32
    const int*    __restrict__ perm,      // [32][NLOC] bucketed loc ids
    const int*    __restrict__ cnts,      // [32]
    float*        __restrict__ out)       // [NFRAMES][NLOC]
{
    __shared__ float4 ltab[NTYPES * KLIVE];   // 76800 B

    const int bucket = blockIdx.x >> 4;       // / KBLK
    const int chunk  = blockIdx.x & (KBLK - 1);
    const int f  = bucket >> 2;
    const int ti = bucket & 3;

    // stage tab[ti][tj][0..1199][:] -> ltab[tj*1200+k] (coalesced float4)
    const float4* tsrc = (const float4*)tab + (size_t)ti * (NTYPES * NSPLINE);
    for (int idx = threadIdx.x; idx < NTYPES * KLIVE; idx += 1024) {
        int tj = idx / KLIVE;
        int k  = idx - tj * KLIVE;
        ltab[idx] = tsrc[tj * NSPLINE + k];
    }
    __syncthreads();

    const float rmin = tab_info[0];
    const float hh   = tab_info[1];
    // CR f32 reciprocal via f64 + single rounding == f32 divide(1,hh) == 200.0f
    float recip = (float)(1.0 / (double)hh);  FP_BAR(recip);

    const int cnt  = cnts[bucket];
    const int lane = threadIdx.x & 63;
    const int wave = (int)(threadIdx.x >> 6); // 0..15
    const int half = lane >> 5;
    const int lih  = lane & 31;
    const size_t fb = (size_t)f * NALL;

    for (int s0 = chunk * 32; s0 < cnt; s0 += KBLK * 32) {
        const int s = s0 + wave * 2 + half;
        const bool active = s < cnt;          // uniform per 32-lane half
        const int loc = active ? perm[(size_t)bucket * NLOC + s] : 0;

        const float4 pl = pack[fb + loc];     // half-uniform broadcast
        const float xl = pl.x, yl = pl.y, zl = pl.z;

        // lanes of this half read their loc's 128 neighbor ids (int4/lane)
        const int4 jj =
            ((const int4*)(nlist + ((size_t)f * NLOC + loc) * NNEI))[lih];
        const int j0 = jj.x, j1 = jj.y, j2 = jj.z, j3 = jj.w;
        const int mj0 = j0 < 0 ? 0 : j0;
        const int mj1 = j1 < 0 ? 0 : j1;
        const int mj2 = j2 < 0 ? 0 : j2;
        const int mj3 = j3 < 0 ? 0 : j3;

        // all four pack gathers issued up front for MLP
        const float4 c0 = pack[fb + mj0];
        const float4 c1 = pack[fb + mj1];
        const float4 c2 = pack[fb + mj2];
        const float4 c3 = pack[fb + mj3];

        double esum = nb_energy_lds(c0, j0 >= 0, xl, yl, zl, rmin, recip, ltab)
                    + nb_energy_lds(c1, j1 >= 0, xl, yl, zl, rmin, recip, ltab)
                    + nb_energy_lds(c2, j2 >= 0, xl, yl, zl, rmin, recip, ltab)
                    + nb_energy_lds(c3, j3 >= 0, xl, yl, zl, rmin, recip, ltab);

        // butterfly within each 32-lane half
#pragma unroll
        for (int off = 16; off >= 1; off >>= 1)
            esum += __shfl_xor(esum, off, 64);

        if (active && lih == 0) out[(size_t)f * NLOC + loc] = (float)(0.5 * esum);
    }
}

// -------- r12 fallback (used only if ws_size is too small) --------
__device__ __forceinline__ double nb_energy_g(
    float4 c, bool valid, float xl, float yl, float zl,
    float rmin, float recip, const float* __restrict__ tabi)
{
    float dx = c.x - xl;  FP_BAR(dx);
    float dy = c.y - yl;  FP_BAR(dy);
    float dz = c.z - zl;  FP_BAR(dz);
    float my = dy * dy;                    FP_BAR(my);
    float t1 = __builtin_fmaf(dx, dx, my); FP_BAR(t1);
    float ss = __builtin_fmaf(dz, dz, t1); FP_BAR(ss);
    float rr = sqrtf(ss);                  FP_BAR(rr);
    float num = rr - rmin;               FP_BAR(num);
    float uu  = num * recip;             FP_BAR(uu);
    int   idx = (int)uu;
    double t  = (double)uu - (double)idx;
    int clip  = idx < 0 ? 0 : (idx > NSPLINE - 1 ? NSPLINE - 1 : idx);
    int tj    = __float_as_int(c.w);
    const float4 coef =
        *(const float4*)(tabi + (((size_t)tj * NSPLINE + clip) << 2));
    double e = (((double)coef.x * t + (double)coef.y) * t + (double)coef.z) * t
               + (double)coef.w;
    bool zero = (!valid) | (idx > NSPLINE) | (rr >= 6.0f);
    return zero ? 0.0 : e;
}

__global__ __launch_bounds__(256) void pairtab_kernel(
    const float4* __restrict__ pack, const float* __restrict__ tab,
    const float* __restrict__ tab_info, const int* __restrict__ nlist,
    float* __restrict__ out)
{
    const int lane = threadIdx.x & 63;
    const int wid  = (blockIdx.x * 256 + threadIdx.x) >> 6;
    const int half = lane >> 5;
    const int gloc = 2 * wid + half;
    const int f = gloc >> 13;
    const int i = gloc & (NLOC - 1);
    const float rmin = tab_info[0];
    const float hh   = tab_info[1];
    float recip = (float)(1.0 / (double)hh);  FP_BAR(recip);
    const float4 pl = pack[(size_t)f * NALL + i];
    const float xl = pl.x, yl = pl.y, zl = pl.z;
    const int   ti = __float_as_int(pl.w);
    const float* tabi = tab + (size_t)ti * (NTYPES * NSPLINE * 4);
    const int4 jj = ((const int4*)(nlist + (size_t)wid * 256))[lane];
    const int j0 = jj.x, j1 = jj.y, j2 = jj.z, j3 = jj.w;
    const int mj0 = j0 < 0 ? 0 : j0, mj1 = j1 < 0 ? 0 : j1;
    const int mj2 = j2 < 0 ? 0 : j2, mj3 = j3 < 0 ? 0 : j3;
    const size_t fb = (size_t)f * NALL;
    const float4 c0 = pack[fb + mj0], c1 = pack[fb + mj1];
    const float4 c2 = pack[fb + mj2], c3 = pack[fb + mj3];
    double esum = nb_energy_g(c0, j0 >= 0, xl, yl, zl, rmin, recip, tabi)
                + nb_energy_g(c1, j1 >= 0, xl, yl, zl, rmin, recip, tabi)
                + nb_energy_g(c2, j2 >= 0, xl, yl, zl, rmin, recip, tabi)
                + nb_energy_g(c3, j3 >= 0, xl, yl, zl, rmin, recip, tabi);
#pragma unroll
    for (int off = 16; off >= 1; off >>= 1)
        esum += __shfl_xor(esum, off, 64);
    if ((lane & 31) == 0) out[gloc] = (float)(0.5 * esum);
}

extern "C" void kernel_launch(void* const* d_in, const int* in_sizes, int n_in,
                              void* d_out, int out_size, void* d_ws, size_t ws_size,
                              hipStream_t stream)
{
    const float* coord   = (const float*)d_in[0];   // (8,16384,3) f32
    const float* tab     = (const float*)d_in[1];   // (4,4,2000,4) f32
    const float* tabinfo = (const float*)d_in[2];   // (4,) f32
    const int*   atype   = (const int*)d_in[3];     // (8,16384) int32
    const int*   nlist   = (const int*)d_in[4];     // (8,8192,128) int32
    float* out  = (float*)d_out;                    // (8,8192,1) f32

    // ws layout: pack 2MB | perm 1MB | cnts 128B
    float4* pack = (float4*)d_ws;
    int*    perm = (int*)((char*)d_ws + 2 * 1024 * 1024);
    int*    cnts = (int*)((char*)d_ws + 3 * 1024 * 1024);
    const size_t need = 3 * 1024 * 1024 + 128;

    pack_kernel<<<(NFRAMES * NALL) / 256, 256, 0, stream>>>(coord, atype, pack);

    if (ws_size >= need) {
        zero_counts_kernel<<<1, 64, 0, stream>>>(cnts);
        bucket_kernel<<<(NFRAMES * NLOC) / 256, 256, 0, stream>>>(atype, perm, cnts);
        pairtab_lds_kernel<<<NFRAMES * NTYPES * KBLK, 1024, 0, stream>>>(
            pack, tab, tabinfo, nlist, perm, cnts, out);
    } else {
        pairtab_kernel<<<(NFRAMES * NLOC) / 8, 256, 0, stream>>>(
            pack, tab, tabinfo, nlist, out);
    }
}

// Round 14
// 117.320 us; speedup vs baseline: 2.5349x; 2.5349x over previous
//
#include <hip/hip_runtime.h>

// Problem constants: nframes=8, nloc=8192, nnei=128, nall=16384, ntypes=4,
// nspline=2000. rmin=0, hh=f32(0.005), rcut=6.0.
constexpr int NFRAMES = 8;
constexpr int NLOC    = 8192;
constexpr int NNEI    = 128;
constexpr int NALL    = 16384;
constexpr int NTYPES  = 4;
constexpr int NSPLINE = 2000;
constexpr int KLIVE   = 1200;   // rr<6 => uu=rr*200<1200 => live bins [0,1200)
constexpr int KBLK    = 16;     // chunks (blocks) per (frame,type) bucket

// Opaque dataflow barrier: keeps the verified f32 rounding chain intact.
#define FP_BAR(x) asm volatile("" : "+v"(x))

// pack + zero the 32 bucket counters (saves a launch; stream-ordered before
// bucket_kernel).
__global__ __launch_bounds__(256) void pack_kernel(
    const float* __restrict__ coord, const int* __restrict__ atype,
    float4* __restrict__ pack, int* __restrict__ cnts)
{
    int t = blockIdx.x * 256 + threadIdx.x;   // grid sized exactly
    if (blockIdx.x == 0 && threadIdx.x < NFRAMES * NTYPES) cnts[threadIdx.x] = 0;
    float4 v;
    v.x = coord[3 * (size_t)t + 0];
    v.y = coord[3 * (size_t)t + 1];
    v.z = coord[3 * (size_t)t + 2];
    v.w = __int_as_float(atype[t]);
    pack[t] = v;
}

// r13 post-mortem: 65536 global atomics on 32 counters = 2048 serialized
// round-trips/counter = 179us. r14: per-block LDS histogram -> ONE global
// atomic per (block,type) = 1024 total (32/counter) -> ~3us.
__global__ __launch_bounds__(256) void bucket_kernel(
    const int* __restrict__ atype, int* __restrict__ perm,
    int* __restrict__ cnts)
{
    __shared__ int hist[NTYPES];
    __shared__ int base[NTYPES];
    const int t = blockIdx.x * 256 + threadIdx.x;   // 0..65535
    const int f = t >> 13;                          // block-uniform (256|8192)
    const int i = t & (NLOC - 1);
    const int ty = atype[(size_t)f * NALL + i];

    if (threadIdx.x < NTYPES) hist[threadIdx.x] = 0;
    __syncthreads();
    const int my_off = atomicAdd(&hist[ty], 1);     // LDS atomic (fast)
    __syncthreads();
    if (threadIdx.x < NTYPES)
        base[threadIdx.x] = atomicAdd(&cnts[f * NTYPES + threadIdx.x],
                                      hist[threadIdx.x]);
    __syncthreads();
    perm[(size_t)(f * NTYPES + ty) * NLOC + base[ty] + my_off] = i;
}

// VERIFIED ref chain (r11, absmax 3.8e-6 — DO NOT TOUCH):
//   ss = fma(dz,dz, fma(dx,dx, dy*dy)); rr = CR sqrtf; uu = rr * f32(1/hh);
//   idx = trunc(uu); poly/sum in f64 (post-bin). Energy zero iff
//   !valid | rr>=6; live => idx in [0,1199] (validated in r13, same absmax).
__device__ __forceinline__ double nb_energy_lds(
    float4 c, bool valid, float xl, float yl, float zl,
    float rmin, float recip, const float4* __restrict__ ltab)
{
    float dx = c.x - xl;  FP_BAR(dx);
    float dy = c.y - yl;  FP_BAR(dy);
    float dz = c.z - zl;  FP_BAR(dz);
    float my = dy * dy;                    FP_BAR(my);
    float t1 = __builtin_fmaf(dx, dx, my); FP_BAR(t1);   // canonical inner
    float ss = __builtin_fmaf(dz, dz, t1); FP_BAR(ss);
    float rr = sqrtf(ss);                  FP_BAR(rr);   // CR
    float num = rr - rmin;               FP_BAR(num);    // rmin=0: num==rr
    float uu  = num * recip;             FP_BAR(uu);     // recip-mul form
    double e = 0.0;
    if (valid && rr < 6.0f) {
        int    idx = (int)uu;                // in [0,1199] here
        double t   = (double)uu - (double)idx;           // exact (Sterbenz)
        int    tj  = __float_as_int(c.w);
        float4 cf  = ltab[tj * KLIVE + idx];             // ds_read_b128
        e = (((double)cf.x * t + (double)cf.y) * t + (double)cf.z) * t
            + (double)cf.w;
    }
    return e;
}

// r14: __launch_bounds__(1024, 8) forces VGPR<=64 so 2 blocks/CU co-reside
// with 2x76.8KB LDS -> 32 waves/CU (r13 likely fell to 1 block/CU = 16
// waves -> ~110us). Coef gathers on the LDS pipe; TA-pipe requests drop
// 16.8M -> ~9.7M vs r12.
__global__ __launch_bounds__(1024, 8) void pairtab_lds_kernel(
    const float4* __restrict__ pack,
    const float*  __restrict__ tab,       // [NTYPES][NTYPES][NSPLINE][4]
    const float*  __restrict__ tab_info,  // [rmin, hh, nspline, ntypes]
    const int*    __restrict__ nlist,     // [NFRAMES][NLOC][NNEI] int32
    const int*    __restrict__ perm,      // [32][NLOC] bucketed loc ids
    const int*    __restrict__ cnts,      // [32]
    float*        __restrict__ out)       // [NFRAMES][NLOC]
{
    __shared__ float4 ltab[NTYPES * KLIVE];   // 76800 B

    const int bucket = blockIdx.x >> 4;       // / KBLK
    const int chunk  = blockIdx.x & (KBLK - 1);
    const int f  = bucket >> 2;
    const int ti = bucket & 3;

    // stage tab[ti][tj][0..1199][:] -> ltab[tj*1200+k] (coalesced float4)
    const float4* tsrc = (const float4*)tab + (size_t)ti * (NTYPES * NSPLINE);
    for (int idx = threadIdx.x; idx < NTYPES * KLIVE; idx += 1024) {
        int tj = idx / KLIVE;
        int k  = idx - tj * KLIVE;
        ltab[idx] = tsrc[tj * NSPLINE + k];
    }
    __syncthreads();

    const float rmin = tab_info[0];
    const float hh   = tab_info[1];
    // CR f32 reciprocal via f64 + single rounding == f32 divide(1,hh) == 200.0f
    float recip = (float)(1.0 / (double)hh);  FP_BAR(recip);

    const int cnt  = cnts[bucket];
    const int lane = threadIdx.x & 63;
    const int wave = (int)(threadIdx.x >> 6); // 0..15
    const int half = lane >> 5;
    const int lih  = lane & 31;
    const size_t fb = (size_t)f * NALL;

    for (int s0 = chunk * 32; s0 < cnt; s0 += KBLK * 32) {
        const int s = s0 + wave * 2 + half;
        const bool active = s < cnt;          // uniform per 32-lane half
        const int loc = active ? perm[(size_t)bucket * NLOC + s] : 0;

        const float4 pl = pack[fb + loc];     // half-uniform broadcast
        const float xl = pl.x, yl = pl.y, zl = pl.z;

        // lanes of this half read their loc's 128 neighbor ids (int4/lane)
        const int4 jj =
            ((const int4*)(nlist + ((size_t)f * NLOC + loc) * NNEI))[lih];
        const int mj0 = jj.x < 0 ? 0 : jj.x;
        const int mj1 = jj.y < 0 ? 0 : jj.y;
        const int mj2 = jj.z < 0 ? 0 : jj.z;
        const int mj3 = jj.w < 0 ? 0 : jj.w;

        // all four pack gathers issued up front for MLP
        const float4 c0 = pack[fb + mj0];
        const float4 c1 = pack[fb + mj1];
        const float4 c2 = pack[fb + mj2];
        const float4 c3 = pack[fb + mj3];

        double esum = nb_energy_lds(c0, jj.x >= 0, xl, yl, zl, rmin, recip, ltab)
                    + nb_energy_lds(c1, jj.y >= 0, xl, yl, zl, rmin, recip, ltab)
                    + nb_energy_lds(c2, jj.z >= 0, xl, yl, zl, rmin, recip, ltab)
                    + nb_energy_lds(c3, jj.w >= 0, xl, yl, zl, rmin, recip, ltab);

        // butterfly within each 32-lane half
#pragma unroll
        for (int off = 16; off >= 1; off >>= 1)
            esum += __shfl_xor(esum, off, 64);

        if (active && lih == 0) out[(size_t)f * NLOC + loc] = (float)(0.5 * esum);
    }
}

// -------- r12 fallback (used only if ws_size is too small) --------
__device__ __forceinline__ double nb_energy_g(
    float4 c, bool valid, float xl, float yl, float zl,
    float rmin, float recip, const float* __restrict__ tabi)
{
    float dx = c.x - xl;  FP_BAR(dx);
    float dy = c.y - yl;  FP_BAR(dy);
    float dz = c.z - zl;  FP_BAR(dz);
    float my = dy * dy;                    FP_BAR(my);
    float t1 = __builtin_fmaf(dx, dx, my); FP_BAR(t1);
    float ss = __builtin_fmaf(dz, dz, t1); FP_BAR(ss);
    float rr = sqrtf(ss);                  FP_BAR(rr);
    float num = rr - rmin;               FP_BAR(num);
    float uu  = num * recip;             FP_BAR(uu);
    int   idx = (int)uu;
    double t  = (double)uu - (double)idx;
    int clip  = idx < 0 ? 0 : (idx > NSPLINE - 1 ? NSPLINE - 1 : idx);
    int tj    = __float_as_int(c.w);
    const float4 coef =
        *(const float4*)(tabi + (((size_t)tj * NSPLINE + clip) << 2));
    double e = (((double)coef.x * t + (double)coef.y) * t + (double)coef.z) * t
               + (double)coef.w;
    bool zero = (!valid) | (idx > NSPLINE) | (rr >= 6.0f);
    return zero ? 0.0 : e;
}

__global__ __launch_bounds__(256) void pairtab_kernel(
    const float4* __restrict__ pack, const float* __restrict__ tab,
    const float* __restrict__ tab_info, const int* __restrict__ nlist,
    float* __restrict__ out)
{
    const int lane = threadIdx.x & 63;
    const int wid  = (blockIdx.x * 256 + threadIdx.x) >> 6;
    const int half = lane >> 5;
    const int gloc = 2 * wid + half;
    const int f = gloc >> 13;
    const int i = gloc & (NLOC - 1);
    const float rmin = tab_info[0];
    const float hh   = tab_info[1];
    float recip = (float)(1.0 / (double)hh);  FP_BAR(recip);
    const float4 pl = pack[(size_t)f * NALL + i];
    const float xl = pl.x, yl = pl.y, zl = pl.z;
    const int   ti = __float_as_int(pl.w);
    const float* tabi = tab + (size_t)ti * (NTYPES * NSPLINE * 4);
    const int4 jj = ((const int4*)(nlist + (size_t)wid * 256))[lane];
    const int mj0 = jj.x < 0 ? 0 : jj.x, mj1 = jj.y < 0 ? 0 : jj.y;
    const int mj2 = jj.z < 0 ? 0 : jj.z, mj3 = jj.w < 0 ? 0 : jj.w;
    const size_t fb = (size_t)f * NALL;
    const float4 c0 = pack[fb + mj0], c1 = pack[fb + mj1];
    const float4 c2 = pack[fb + mj2], c3 = pack[fb + mj3];
    double esum = nb_energy_g(c0, jj.x >= 0, xl, yl, zl, rmin, recip, tabi)
                + nb_energy_g(c1, jj.y >= 0, xl, yl, zl, rmin, recip, tabi)
                + nb_energy_g(c2, jj.z >= 0, xl, yl, zl, rmin, recip, tabi)
                + nb_energy_g(c3, jj.w >= 0, xl, yl, zl, rmin, recip, tabi);
#pragma unroll
    for (int off = 16; off >= 1; off >>= 1)
        esum += __shfl_xor(esum, off, 64);
    if ((lane & 31) == 0) out[gloc] = (float)(0.5 * esum);
}

extern "C" void kernel_launch(void* const* d_in, const int* in_sizes, int n_in,
                              void* d_out, int out_size, void* d_ws, size_t ws_size,
                              hipStream_t stream)
{
    const float* coord   = (const float*)d_in[0];   // (8,16384,3) f32
    const float* tab     = (const float*)d_in[1];   // (4,4,2000,4) f32
    const float* tabinfo = (const float*)d_in[2];   // (4,) f32
    const int*   atype   = (const int*)d_in[3];     // (8,16384) int32
    const int*   nlist   = (const int*)d_in[4];     // (8,8192,128) int32
    float* out  = (float*)d_out;                    // (8,8192,1) f32

    // ws layout: pack 2MB | perm 1MB | cnts 128B
    float4* pack = (float4*)d_ws;
    int*    perm = (int*)((char*)d_ws + 2 * 1024 * 1024);
    int*    cnts = (int*)((char*)d_ws + 3 * 1024 * 1024);
    const size_t need = 3 * 1024 * 1024 + 128;

    pack_kernel<<<(NFRAMES * NALL) / 256, 256, 0, stream>>>(coord, atype, pack,
                                                            cnts);
    if (ws_size >= need) {
        bucket_kernel<<<(NFRAMES * NLOC) / 256, 256, 0, stream>>>(atype, perm, cnts);
        pairtab_lds_kernel<<<NFRAMES * NTYPES * KBLK, 1024, 0, stream>>>(
            pack, tab, tabinfo, nlist, perm, cnts, out);
    } else {
        pairtab_kernel<<<(NFRAMES * NLOC) / 8, 256, 0, stream>>>(
            pack, tab, tabinfo, nlist, out);
    }
}